// Round 5
// baseline (85.371 us; speedup 1.0000x reference)
//
#include <hip/hip_runtime.h>
#include <hip/hip_bf16.h>

#define HH 512
#define BB 8192
#define KK 1536
#define NT 48              // K tiles of 32
#define HB 4194304         // 512*8192
#define BLOB 8192          // bhalf per 16KB blob

typedef __bf16 bhalf;
typedef __bf16 bf16x8 __attribute__((ext_vector_type(8)));
typedef float  f32x4  __attribute__((ext_vector_type(4)));

typedef __attribute__((address_space(1))) void* as1_t;
typedef __attribute__((address_space(3))) void* as3_t;

#define GLDS(src, dst) __builtin_amdgcn_global_load_lds((as1_t)(void*)(src), (as3_t)(void*)(dst), 16, 0, 0)
#define SBAR() asm volatile("s_barrier" ::: "memory")
#define VM8()  asm volatile("s_waitcnt vmcnt(8)" ::: "memory")
#define VM6()  asm volatile("s_waitcnt vmcnt(6)" ::: "memory")
#define VM4()  asm volatile("s_waitcnt vmcnt(4)" ::: "memory")
#define VM0()  asm volatile("s_waitcnt vmcnt(0)" ::: "memory")

// Packed blob layout (k-major, conflict-free): blob = one (256-row, 32-k)
// tile = 16 KB.  slot s = rb*64 + hi*16 + lr.  Element (row rb*16+lr,
// k hi*8+e) at bhalf offset s*8+e.  Fragment reads hit all 32 banks once
// per 8-lane group -> zero bank conflicts (verified R4: counter == 0).

// ---------------------------------------------------------------------------
// prep_x: pack scaled+transposed+bf16 X into blobs [nt][kt].
// ---------------------------------------------------------------------------
__global__ __launch_bounds__(256) void prep_x(
    const float* __restrict__ h, const float* __restrict__ ht,
    const float* __restrict__ hb, const float* __restrict__ z,
    const float* __restrict__ zb, bhalf* __restrict__ XtP)
{
    __shared__ float tile[32][257];
    const int tid = threadIdx.x;
    const int kt  = blockIdx.x;          // 0..47
    const int nt  = blockIdx.y;          // 0..31
    const int n   = nt * 256 + tid;
    const int kb  = kt * 32;

    const float* src; int kr; float scale;
    if (kb < 512)       { src = h;  kr = kb;        scale = 1.f - z[n]; }
    else if (kb < 1024) { src = ht; kr = kb - 512;  scale = z[n]; }
    else                { src = hb; kr = kb - 1024; scale = zb[n]; }

    #pragma unroll
    for (int kk = 0; kk < 32; ++kk)
        tile[kk][tid] = src[(size_t)(kr + kk) * BB + n] * scale;
    __syncthreads();

    bhalf* blob = XtP + (size_t)(nt * NT + kt) * BLOB;
    #pragma unroll
    for (int q = 0; q < 4; ++q) {
        const int s  = q * 256 + tid;
        const int rb = s >> 6, w = s & 63;
        const int hh = w >> 4, lrr = w & 15;      // slot = rb*64 + hh*16 + lrr
        const int nloc = rb * 16 + lrr, kloc = hh * 8;
        bf16x8 r;
        #pragma unroll
        for (int e = 0; e < 8; ++e) r[e] = (bhalf)tile[kloc + e][nloc];
        *(bf16x8*)(blob + s * 8) = r;
    }
}

// ---------------------------------------------------------------------------
// prep_w: pack gate-interleaved weights into blobs [mt][kt]; source-coalesced.
// ---------------------------------------------------------------------------
__global__ __launch_bounds__(256) void prep_w(
    const float* __restrict__ U11, const float* __restrict__ U21,
    const float* __restrict__ W01, bhalf* __restrict__ WcP)
{
    const int o    = blockIdx.x * 4 + (threadIdx.x >> 6);   // 0..2047
    const int lane = threadIdx.x & 63;
    const int g = o >> 9, j = o & 511;
    const int mp = 4 * j + g;
    const int mt = mp >> 8, rb = (mp >> 4) & 15, lrr = mp & 15;

    #pragma unroll
    for (int p = 0; p < 3; ++p) {
        const float* src = (p == 0) ? U11 : (p == 1) ? U21 : W01;
        const float* rp  = src + (size_t)o * 512 + lane * 8;
        float4 v0 = *(const float4*)rp;
        float4 v1 = *(const float4*)(rp + 4);
        bf16x8 r;
        r[0]=(bhalf)v0.x; r[1]=(bhalf)v0.y; r[2]=(bhalf)v0.z; r[3]=(bhalf)v0.w;
        r[4]=(bhalf)v1.x; r[5]=(bhalf)v1.y; r[6]=(bhalf)v1.z; r[7]=(bhalf)v1.w;
        const int kt = p * 16 + (lane >> 2);
        const int hh = lane & 3;
        *(bf16x8*)(WcP + (size_t)(mt * NT + kt) * BLOB
                   + rb * 512 + hh * 128 + lrr * 8) = r;
    }
}

// ---------------------------------------------------------------------------
__device__ __forceinline__ float sigmf(float x)    { return 1.f / (1.f + __expf(-x)); }
__device__ __forceinline__ float tanhfast(float x) { return 2.f / (1.f + __expf(-2.f * x)) - 1.f; }

// ---------------------------------------------------------------------------
// gemm_fused: BM=BN=256, 8 waves (2Mx4N), 4 LDS buffers of K-32 blobs,
// 8-phase-style schedule: 96 flat phases, each {ds_read next phase's frags ||
// 2 global_load_lds || barrier || 16 MFMA (setprio) || barrier}; counted
// vmcnt(6) once per tile, never drained.  Fused gate epilogue.
// ---------------------------------------------------------------------------
__global__ __launch_bounds__(512, 2) void gemm_fused(
    const bhalf* __restrict__ WcP, const bhalf* __restrict__ XtP,
    const float* __restrict__ bias, const float* __restrict__ c_in,
    const float* __restrict__ h_in, const float* __restrict__ z,
    const float* __restrict__ zb, float* __restrict__ out)
{
    __shared__ bhalf As[4][BLOB];
    __shared__ bhalf Bs[4][BLOB];

    const int tid  = threadIdx.x;
    const int lane = tid & 63;
    const int wid  = tid >> 6;
    const int wm   = wid >> 2, wn = wid & 3;
    const int lr   = lane & 15, hi = lane >> 4;
    const int soff = hi * 128 + lr * 8;      // k-major fragment offset (bhalf)

    const int xcd = blockIdx.x & 7;
    const int i   = blockIdx.x >> 3;
    const int mt  = i & 7;
    const int nt  = xcd * 4 + (i >> 3);
    const int m0 = mt * 256, n0 = nt * 256;

    const bhalf* gA = WcP + (size_t)mt * (NT * BLOB) + tid * 8;
    const bhalf* gB = XtP + (size_t)nt * (NT * BLOB) + tid * 8;

    const bhalf* pA0 = &As[0][wm * 4096 + soff];
    const bhalf* pA1 = &As[1][wm * 4096 + soff];
    const bhalf* pA2 = &As[2][wm * 4096 + soff];
    const bhalf* pA3 = &As[3][wm * 4096 + soff];
    const bhalf* pB0 = &Bs[0][wn * 2048 + soff];
    const bhalf* pB1 = &Bs[1][wn * 2048 + soff];
    const bhalf* pB2 = &Bs[2][wn * 2048 + soff];
    const bhalf* pB3 = &Bs[3][wn * 2048 + soff];

#define STAGE_A(t, bf) do { const bhalf* s_ = gA + (size_t)(t) * BLOB;        \
        GLDS(s_, &As[bf][tid * 8]); GLDS(s_ + 4096, &As[bf][tid * 8 + 4096]); } while (0)
#define STAGE_B(t, bf) do { const bhalf* s_ = gB + (size_t)(t) * BLOB;        \
        GLDS(s_, &Bs[bf][tid * 8]); GLDS(s_ + 4096, &Bs[bf][tid * 8 + 4096]); } while (0)

#define RDA(bf, i_) (*(const bf16x8*)(pA##bf + (i_) * 512))
#define RDB(bf, i_) (*(const bf16x8*)(pB##bf + (i_) * 512))

#define MF(mi, ni, A_, B_) acc[mi][ni] = \
    __builtin_amdgcn_mfma_f32_16x16x32_bf16(A_, B_, acc[mi][ni], 0, 0, 0)

#define CL_LO(B0,B1,B2,B3) do { __builtin_amdgcn_s_setprio(1);                \
    MF(0,0,aL0,B0); MF(0,1,aL0,B1); MF(0,2,aL0,B2); MF(0,3,aL0,B3);           \
    MF(1,0,aL1,B0); MF(1,1,aL1,B1); MF(1,2,aL1,B2); MF(1,3,aL1,B3);           \
    MF(2,0,aL2,B0); MF(2,1,aL2,B1); MF(2,2,aL2,B2); MF(2,3,aL2,B3);           \
    MF(3,0,aL3,B0); MF(3,1,aL3,B1); MF(3,2,aL3,B2); MF(3,3,aL3,B3);           \
    __builtin_amdgcn_s_setprio(0); } while (0)

#define CL_HI(B0,B1,B2,B3) do { __builtin_amdgcn_s_setprio(1);                \
    MF(4,0,aH0,B0); MF(4,1,aH0,B1); MF(4,2,aH0,B2); MF(4,3,aH0,B3);           \
    MF(5,0,aH1,B0); MF(5,1,aH1,B1); MF(5,2,aH1,B2); MF(5,3,aH1,B3);           \
    MF(6,0,aH2,B0); MF(6,1,aH2,B1); MF(6,2,aH2,B2); MF(6,3,aH2,B3);           \
    MF(7,0,aH3,B0); MF(7,1,aH3,B1); MF(7,2,aH3,B2); MF(7,3,aH3,B3);           \
    __builtin_amdgcn_s_setprio(0); } while (0)

// phase h0 of tile in buf `bfc`: read aHI(bfc), stage A(tst->bfst), MFMA lo
#define PH0(bfc, tst, bfst, DOST, B0,B1,B2,B3) do {                           \
    aH0 = RDA(bfc,4); aH1 = RDA(bfc,5); aH2 = RDA(bfc,6); aH3 = RDA(bfc,7);   \
    if (DOST) STAGE_A(tst, bfst);                                             \
    SBAR(); CL_LO(B0,B1,B2,B3); SBAR(); } while (0)

// phase h1: vm-wait, read next tile (buf bfn) b+aLO, stage B, MFMA hi
#define PH1(bfn, tst, bfst, DOST, DORD, VMW, B0,B1,B2,B3, N0,N1,N2,N3) do {   \
    VMW;                                                                      \
    if (DORD) { N0 = RDB(bfn,0); N1 = RDB(bfn,1); N2 = RDB(bfn,2);            \
                N3 = RDB(bfn,3);                                              \
                aL0 = RDA(bfn,0); aL1 = RDA(bfn,1); aL2 = RDA(bfn,2);         \
                aL3 = RDA(bfn,3); }                                           \
    if (DOST) STAGE_B(tst, bfst);                                             \
    SBAR(); CL_HI(B0,B1,B2,B3); SBAR(); } while (0)

    f32x4 acc[8][4] = {};
    bf16x8 aL0, aL1, aL2, aL3, aH0, aH1, aH2, aH3;
    bf16x8 bA0, bA1, bA2, bA3, bB0, bB1, bB2, bB3;

    // prologue: stage tiles 0..2, wait tile 0, preload its b + aLO
    STAGE_A(0, 0); STAGE_B(0, 0);
    STAGE_A(1, 1); STAGE_B(1, 1);
    STAGE_A(2, 2); STAGE_B(2, 2);
    VM8(); SBAR();
    bA0 = RDB(0,0); bA1 = RDB(0,1); bA2 = RDB(0,2); bA3 = RDB(0,3);
    aL0 = RDA(0,0); aL1 = RDA(0,1); aL2 = RDA(0,2); aL3 = RDA(0,3);

#define QUAD(base) do {                                                       \
    PH0(0, (base)+3, 3, 1, bA0,bA1,bA2,bA3);                                  \
    PH1(1, (base)+3, 3, 1, 1, VM6(), bA0,bA1,bA2,bA3, bB0,bB1,bB2,bB3);       \
    PH0(1, (base)+4, 0, 1, bB0,bB1,bB2,bB3);                                  \
    PH1(2, (base)+4, 0, 1, 1, VM6(), bB0,bB1,bB2,bB3, bA0,bA1,bA2,bA3);       \
    PH0(2, (base)+5, 1, 1, bA0,bA1,bA2,bA3);                                  \
    PH1(3, (base)+5, 1, 1, 1, VM6(), bA0,bA1,bA2,bA3, bB0,bB1,bB2,bB3);       \
    PH0(3, (base)+6, 2, 1, bB0,bB1,bB2,bB3);                                  \
    PH1(0, (base)+6, 2, 1, 1, VM6(), bB0,bB1,bB2,bB3, bA0,bA1,bA2,bA3);       \
} while (0)

    for (int base = 0; base < 44; base += 4) {   // tiles 0..43, stage 3..46
        QUAD(base);
    }
    // t=44 (buf0, bA): stage tile 47 -> buf3
    PH0(0, 47, 3, 1, bA0,bA1,bA2,bA3);
    PH1(1, 47, 3, 1, 1, VM6(), bA0,bA1,bA2,bA3, bB0,bB1,bB2,bB3);
    // t=45 (buf1, bB)
    PH0(1, 0, 0, 0, bB0,bB1,bB2,bB3);
    PH1(2, 0, 0, 0, 1, VM4(), bB0,bB1,bB2,bB3, bA0,bA1,bA2,bA3);
    // t=46 (buf2, bA)
    PH0(2, 0, 0, 0, bA0,bA1,bA2,bA3);
    PH1(3, 0, 0, 0, 1, VM0(), bA0,bA1,bA2,bA3, bB0,bB1,bB2,bB3);
    // t=47 (buf3, bB)
    PH0(3, 0, 0, 0, bB0,bB1,bB2,bB3);
    PH1(0, 0, 0, 0, 0, ((void)0), bB0,bB1,bB2,bB3, bA0,bA1,bA2,bA3);

    // ---- fused gate epilogue: acc[mi][ni][r] = gate r of hidden j ----
    const int colbase = n0 + wn * 64 + lr;
    float zc[4], zbc[4];
    #pragma unroll
    for (int ni = 0; ni < 4; ++ni) {
        zc[ni]  = z[colbase + ni * 16];
        zbc[ni] = zb[colbase + ni * 16];
    }
    #pragma unroll
    for (int mi = 0; mi < 8; ++mi) {
        const int j = (m0 >> 2) + wm * 32 + mi * 4 + hi;
        const float bf_ = bias[j];
        const float bi_ = bias[512 + j];
        const float bo_ = bias[1024 + j];
        const float bg_ = bias[1536 + j];
        #pragma unroll
        for (int ni = 0; ni < 4; ++ni) {
            const int col = colbase + ni * 16;
            const size_t idx = (size_t)j * BB + col;
            const float cv = c_in[idx];
            const float hv = h_in[idx];
            const float fv = sigmf(acc[mi][ni][0] + bf_);
            const float iv = sigmf(acc[mi][ni][1] + bi_);
            const float ov = sigmf(acc[mi][ni][2] + bo_);
            const float gv = tanhfast(acc[mi][ni][3] + bg_);
            const float ig = iv * gv;
            const float zq = zc[ni], zbq = zbc[ni];
            const float cn = zq * ig + (1.f - zq) * (1.f - zbq) * cv
                           + (1.f - zq) * zbq * (fv * cv + ig);
            const float tc = tanhfast(cn);
            const float hn = (zq + (1.f - zq) * zbq) * ov * tc
                           + (1.f - zq) * (1.f - zbq) * hv;
            out[idx]      = hn;
            out[HB + idx] = cn;
        }
    }
}

// ---------------------------------------------------------------------------
// zhat: row 2048 GEMV over packed Xt (bf16).
// ---------------------------------------------------------------------------
__global__ __launch_bounds__(256) void zhat_k(
    const bhalf* __restrict__ XtP, const float* __restrict__ U11,
    const float* __restrict__ U21, const float* __restrict__ W01,
    const float* __restrict__ bias, float* __restrict__ out)
{
    __shared__ float wlds[1536];
    __shared__ float red[8][32];
    const int tid = threadIdx.x;
    for (int idx = tid; idx < 1536; idx += 256) {
        float v;
        if (idx < 512)       v = U11[1048576 + idx];
        else if (idx < 1024) v = U21[1048576 + idx - 512];
        else                 v = W01[1048576 + idx - 1024];
        wlds[idx] = v;
    }
    __syncthreads();

    const int col = tid & 31, kg = tid >> 5;
    const int n = blockIdx.x * 32 + col;
    const int nt = n >> 8, rb = (n >> 4) & 15, lrr = n & 15;
    const bhalf* base = XtP + (size_t)nt * (NT * BLOB) + rb * 512;

    float acc = 0.f;
    for (int kt = kg * 6; kt < kg * 6 + 6; ++kt) {
        #pragma unroll
        for (int hh = 0; hh < 4; ++hh) {
            bf16x8 v = *(const bf16x8*)(base + (size_t)kt * BLOB + hh * 128 + lrr * 8);
            #pragma unroll
            for (int e = 0; e < 8; ++e)
                acc += (float)v[e] * wlds[kt * 32 + hh * 8 + e];
        }
    }
    red[kg][col] = acc;
    __syncthreads();
    if (tid < 32) {
        float s = 0.f;
        #pragma unroll
        for (int k2 = 0; k2 < 8; ++k2) s += red[k2][tid];
        const float v = (s + bias[2048] + 1.f) * 0.5f;
        out[(size_t)2 * HB + blockIdx.x * 32 + tid] = fminf(fmaxf(v, 0.f), 1.f);
    }
}

// ---------------------------------------------------------------------------
extern "C" void kernel_launch(void* const* d_in, const int* in_sizes, int n_in,
                              void* d_out, int out_size, void* d_ws, size_t ws_size,
                              hipStream_t stream) {
    const float* c    = (const float*)d_in[0];
    const float* hb   = (const float*)d_in[1];
    const float* h    = (const float*)d_in[2];
    const float* ht   = (const float*)d_in[3];
    const float* z    = (const float*)d_in[4];
    const float* zb   = (const float*)d_in[5];
    const float* U11  = (const float*)d_in[6];
    const float* U21  = (const float*)d_in[7];
    const float* W01  = (const float*)d_in[8];
    const float* bias = (const float*)d_in[9];
    float* out = (float*)d_out;

    char* ws = (char*)d_ws;
    bhalf* XtP = (bhalf*)ws;                       // 32*48*16KB = 25165824 B
    bhalf* WcP = (bhalf*)(ws + 25165824);          //  8*48*16KB =  6291456 B

    prep_x    <<<dim3(48, 32), 256, 0, stream>>>(h, ht, hb, z, zb, XtP);
    prep_w    <<<512, 256, 0, stream>>>(U11, U21, W01, WcP);
    gemm_fused<<<256, 512, 0, stream>>>(WcP, XtP, bias, c, h, z, zb, out);
    zhat_k    <<<256, 256, 0, stream>>>(XtP, U11, U21, W01, bias, out);
}

// Round 6
// 82.189 us; speedup vs baseline: 1.0387x; 1.0387x over previous
//
#include <hip/hip_runtime.h>
#include <hip/hip_bf16.h>

#define HH 512
#define BB 8192
#define KK 1536
#define NT 48              // K tiles of 32
#define HB 4194304         // 512*8192
#define BLOB 8192          // bhalf per 16KB blob

typedef __bf16 bhalf;
typedef __bf16 bf16x8 __attribute__((ext_vector_type(8)));
typedef float  f32x4  __attribute__((ext_vector_type(4)));

typedef __attribute__((address_space(1))) void* as1_t;
typedef __attribute__((address_space(3))) void* as3_t;

#define GLDS(src, dst) __builtin_amdgcn_global_load_lds((as1_t)(void*)(src), (as3_t)(void*)(dst), 16, 0, 0)
#define SBAR() asm volatile("s_barrier" ::: "memory")
#define VM8()  asm volatile("s_waitcnt vmcnt(8)" ::: "memory")
#define VM4()  asm volatile("s_waitcnt vmcnt(4)" ::: "memory")
#define VM0()  asm volatile("s_waitcnt vmcnt(0)" ::: "memory")

// Packed blob layout (k-major, conflict-free): blob = one (256-row, 32-k)
// tile = 16 KB.  slot s = rb*64 + hi*16 + lr.  Element (row rb*16+lr,
// k hi*8+e) at bhalf offset s*8+e.  Fragment reads hit all 32 banks once
// per 8-lane group -> zero bank conflicts (verified R4: counter == 0).

// ---------------------------------------------------------------------------
// prep_x: pack scaled+transposed+bf16 X into blobs [nt][kt].
// ---------------------------------------------------------------------------
__global__ __launch_bounds__(256) void prep_x(
    const float* __restrict__ h, const float* __restrict__ ht,
    const float* __restrict__ hb, const float* __restrict__ z,
    const float* __restrict__ zb, bhalf* __restrict__ XtP)
{
    __shared__ float tile[32][257];
    const int tid = threadIdx.x;
    const int kt  = blockIdx.x;          // 0..47
    const int nt  = blockIdx.y;          // 0..31
    const int n   = nt * 256 + tid;
    const int kb  = kt * 32;

    const float* src; int kr; float scale;
    if (kb < 512)       { src = h;  kr = kb;        scale = 1.f - z[n]; }
    else if (kb < 1024) { src = ht; kr = kb - 512;  scale = z[n]; }
    else                { src = hb; kr = kb - 1024; scale = zb[n]; }

    #pragma unroll
    for (int kk = 0; kk < 32; ++kk)
        tile[kk][tid] = src[(size_t)(kr + kk) * BB + n] * scale;
    __syncthreads();

    bhalf* blob = XtP + (size_t)(nt * NT + kt) * BLOB;
    #pragma unroll
    for (int q = 0; q < 4; ++q) {
        const int s  = q * 256 + tid;
        const int rb = s >> 6, w = s & 63;
        const int hh = w >> 4, lrr = w & 15;      // slot = rb*64 + hh*16 + lrr
        const int nloc = rb * 16 + lrr, kloc = hh * 8;
        bf16x8 r;
        #pragma unroll
        for (int e = 0; e < 8; ++e) r[e] = (bhalf)tile[kloc + e][nloc];
        *(bf16x8*)(blob + s * 8) = r;
    }
}

// ---------------------------------------------------------------------------
// prep_w: pack gate-interleaved weights into blobs [mt][kt]; source-coalesced.
// ---------------------------------------------------------------------------
__global__ __launch_bounds__(256) void prep_w(
    const float* __restrict__ U11, const float* __restrict__ U21,
    const float* __restrict__ W01, bhalf* __restrict__ WcP)
{
    const int o    = blockIdx.x * 4 + (threadIdx.x >> 6);   // 0..2047
    const int lane = threadIdx.x & 63;
    const int g = o >> 9, j = o & 511;
    const int mp = 4 * j + g;
    const int mt = mp >> 8, rb = (mp >> 4) & 15, lrr = mp & 15;

    #pragma unroll
    for (int p = 0; p < 3; ++p) {
        const float* src = (p == 0) ? U11 : (p == 1) ? U21 : W01;
        const float* rp  = src + (size_t)o * 512 + lane * 8;
        float4 v0 = *(const float4*)rp;
        float4 v1 = *(const float4*)(rp + 4);
        bf16x8 r;
        r[0]=(bhalf)v0.x; r[1]=(bhalf)v0.y; r[2]=(bhalf)v0.z; r[3]=(bhalf)v0.w;
        r[4]=(bhalf)v1.x; r[5]=(bhalf)v1.y; r[6]=(bhalf)v1.z; r[7]=(bhalf)v1.w;
        const int kt = p * 16 + (lane >> 2);
        const int hh = lane & 3;
        *(bf16x8*)(WcP + (size_t)(mt * NT + kt) * BLOB
                   + rb * 512 + hh * 128 + lrr * 8) = r;
    }
}

// ---------------------------------------------------------------------------
__device__ __forceinline__ float sigmf(float x)    { return 1.f / (1.f + __expf(-x)); }
__device__ __forceinline__ float tanhfast(float x) { return 2.f / (1.f + __expf(-2.f * x)) - 1.f; }

// ---------------------------------------------------------------------------
// gemm_fused: BM=BN=256, 8 waves (2Mx4N), 4 LDS buffers of K-32 blobs,
// depth-3 counted-vmcnt prefetch, ONE barrier per K-tile; reads + 32 MFMA
// compiler-interleaved (counted lgkm).  Fused gate epilogue.
// Grid 256 blocks = 1/CU; XCD-chunked swizzle.
// ---------------------------------------------------------------------------
__global__ __launch_bounds__(512, 2) void gemm_fused(
    const bhalf* __restrict__ WcP, const bhalf* __restrict__ XtP,
    const float* __restrict__ bias, const float* __restrict__ c_in,
    const float* __restrict__ h_in, const float* __restrict__ z,
    const float* __restrict__ zb, float* __restrict__ out)
{
    __shared__ bhalf As[4][BLOB];
    __shared__ bhalf Bs[4][BLOB];

    const int tid  = threadIdx.x;
    const int lane = tid & 63;
    const int wid  = tid >> 6;
    const int wm   = wid >> 2, wn = wid & 3;
    const int lr   = lane & 15, hi = lane >> 4;
    const int soff = hi * 128 + lr * 8;      // k-major fragment offset (bhalf)

    const int xcd = blockIdx.x & 7;
    const int i   = blockIdx.x >> 3;
    const int mt  = i & 7;
    const int nt  = xcd * 4 + (i >> 3);
    const int m0 = mt * 256, n0 = nt * 256;

    const bhalf* gA = WcP + (size_t)mt * (NT * BLOB) + tid * 8;
    const bhalf* gB = XtP + (size_t)nt * (NT * BLOB) + tid * 8;

    const bhalf* pA0 = &As[0][wm * 4096 + soff];
    const bhalf* pA1 = &As[1][wm * 4096 + soff];
    const bhalf* pA2 = &As[2][wm * 4096 + soff];
    const bhalf* pA3 = &As[3][wm * 4096 + soff];
    const bhalf* pB0 = &Bs[0][wn * 2048 + soff];
    const bhalf* pB1 = &Bs[1][wn * 2048 + soff];
    const bhalf* pB2 = &Bs[2][wn * 2048 + soff];
    const bhalf* pB3 = &Bs[3][wn * 2048 + soff];

#define STAGE(t, bf) do {                                                     \
        const bhalf* sa_ = gA + (size_t)(t) * BLOB;                           \
        const bhalf* sb_ = gB + (size_t)(t) * BLOB;                           \
        GLDS(sa_, &As[bf][tid * 8]); GLDS(sa_ + 4096, &As[bf][tid * 8 + 4096]); \
        GLDS(sb_, &Bs[bf][tid * 8]); GLDS(sb_ + 4096, &Bs[bf][tid * 8 + 4096]); \
    } while (0)

#define MF(mi, ni, A_, B_) acc[mi][ni] = \
    __builtin_amdgcn_mfma_f32_16x16x32_bf16(A_, B_, acc[mi][ni], 0, 0, 0)

// one K-32 tile from buffer q: 12 ds_read_b128 + 32 MFMA, compiler-scheduled
#define CT(q) do {                                                            \
    bf16x8 b0 = *(const bf16x8*)(pB##q);                                      \
    bf16x8 b1 = *(const bf16x8*)(pB##q + 512);                                \
    bf16x8 b2 = *(const bf16x8*)(pB##q + 1024);                               \
    bf16x8 b3 = *(const bf16x8*)(pB##q + 1536);                               \
    bf16x8 a0 = *(const bf16x8*)(pA##q);                                      \
    bf16x8 a1 = *(const bf16x8*)(pA##q + 512);                                \
    bf16x8 a2 = *(const bf16x8*)(pA##q + 1024);                               \
    bf16x8 a3 = *(const bf16x8*)(pA##q + 1536);                               \
    bf16x8 a4 = *(const bf16x8*)(pA##q + 2048);                               \
    bf16x8 a5 = *(const bf16x8*)(pA##q + 2560);                               \
    bf16x8 a6 = *(const bf16x8*)(pA##q + 3072);                               \
    bf16x8 a7 = *(const bf16x8*)(pA##q + 3584);                               \
    __builtin_amdgcn_s_setprio(1);                                            \
    MF(0,0,a0,b0); MF(0,1,a0,b1); MF(0,2,a0,b2); MF(0,3,a0,b3);               \
    MF(1,0,a1,b0); MF(1,1,a1,b1); MF(1,2,a1,b2); MF(1,3,a1,b3);               \
    MF(2,0,a2,b0); MF(2,1,a2,b1); MF(2,2,a2,b2); MF(2,3,a2,b3);               \
    MF(3,0,a3,b0); MF(3,1,a3,b1); MF(3,2,a3,b2); MF(3,3,a3,b3);               \
    MF(4,0,a4,b0); MF(4,1,a4,b1); MF(4,2,a4,b2); MF(4,3,a4,b3);               \
    MF(5,0,a5,b0); MF(5,1,a5,b1); MF(5,2,a5,b2); MF(5,3,a5,b3);               \
    MF(6,0,a6,b0); MF(6,1,a6,b1); MF(6,2,a6,b2); MF(6,3,a6,b3);               \
    MF(7,0,a7,b0); MF(7,1,a7,b1); MF(7,2,a7,b2); MF(7,3,a7,b3);               \
    __builtin_amdgcn_s_setprio(0);                                            \
} while (0)

    f32x4 acc[8][4] = {};

    // prologue: stage tiles 0..2 (12 gloads in flight)
    STAGE(0, 0); STAGE(1, 1); STAGE(2, 2);

    // tiles 0..43: steady state.  At top of tile t: 12 gloads outstanding
    // (t, t+1, t+2); vmcnt(8) waits for tile t's 4.  One barrier per tile.
    for (int base = 0; base < 44; base += 4) {
        VM8(); SBAR(); STAGE(base + 3, 3); CT(0);
        VM8(); SBAR(); STAGE(base + 4, 0); CT(1);
        VM8(); SBAR(); STAGE(base + 5, 1); CT(2);
        VM8(); SBAR(); STAGE(base + 6, 2); CT(3);
    }
    // t=44: stage 47 -> buf3; t=45..47 drain 8/4/0
    VM8(); SBAR(); STAGE(47, 3); CT(0);
    VM8(); SBAR(); CT(1);
    VM4(); SBAR(); CT(2);
    VM0(); SBAR(); CT(3);

    // ---- fused gate epilogue: acc[mi][ni][r] = gate r of hidden j ----
    const int colbase = n0 + wn * 64 + lr;
    float zc[4], zbc[4];
    #pragma unroll
    for (int ni = 0; ni < 4; ++ni) {
        zc[ni]  = z[colbase + ni * 16];
        zbc[ni] = zb[colbase + ni * 16];
    }
    #pragma unroll
    for (int mi = 0; mi < 8; ++mi) {
        const int j = (m0 >> 2) + wm * 32 + mi * 4 + hi;
        const float bf_ = bias[j];
        const float bi_ = bias[512 + j];
        const float bo_ = bias[1024 + j];
        const float bg_ = bias[1536 + j];
        #pragma unroll
        for (int ni = 0; ni < 4; ++ni) {
            const int col = colbase + ni * 16;
            const size_t idx = (size_t)j * BB + col;
            const float cv = c_in[idx];
            const float hv = h_in[idx];
            const float fv = sigmf(acc[mi][ni][0] + bf_);
            const float iv = sigmf(acc[mi][ni][1] + bi_);
            const float ov = sigmf(acc[mi][ni][2] + bo_);
            const float gv = tanhfast(acc[mi][ni][3] + bg_);
            const float ig = iv * gv;
            const float zq = zc[ni], zbq = zbc[ni];
            const float cn = zq * ig + (1.f - zq) * (1.f - zbq) * cv
                           + (1.f - zq) * zbq * (fv * cv + ig);
            const float tc = tanhfast(cn);
            const float hn = (zq + (1.f - zq) * zbq) * ov * tc
                           + (1.f - zq) * (1.f - zbq) * hv;
            out[idx]      = hn;
            out[HB + idx] = cn;
        }
    }
}

// ---------------------------------------------------------------------------
// zhat: row 2048 GEMV over packed Xt (bf16).
// ---------------------------------------------------------------------------
__global__ __launch_bounds__(256) void zhat_k(
    const bhalf* __restrict__ XtP, const float* __restrict__ U11,
    const float* __restrict__ U21, const float* __restrict__ W01,
    const float* __restrict__ bias, float* __restrict__ out)
{
    __shared__ float wlds[1536];
    __shared__ float red[8][32];
    const int tid = threadIdx.x;
    for (int idx = tid; idx < 1536; idx += 256) {
        float v;
        if (idx < 512)       v = U11[1048576 + idx];
        else if (idx < 1024) v = U21[1048576 + idx - 512];
        else                 v = W01[1048576 + idx - 1024];
        wlds[idx] = v;
    }
    __syncthreads();

    const int col = tid & 31, kg = tid >> 5;
    const int n = blockIdx.x * 32 + col;
    const int nt = n >> 8, rb = (n >> 4) & 15, lrr = n & 15;
    const bhalf* base = XtP + (size_t)nt * (NT * BLOB) + rb * 512;

    float acc = 0.f;
    for (int kt = kg * 6; kt < kg * 6 + 6; ++kt) {
        #pragma unroll
        for (int hh = 0; hh < 4; ++hh) {
            bf16x8 v = *(const bf16x8*)(base + (size_t)kt * BLOB + hh * 128 + lrr * 8);
            #pragma unroll
            for (int e = 0; e < 8; ++e)
                acc += (float)v[e] * wlds[kt * 32 + hh * 8 + e];
        }
    }
    red[kg][col] = acc;
    __syncthreads();
    if (tid < 32) {
        float s = 0.f;
        #pragma unroll
        for (int k2 = 0; k2 < 8; ++k2) s += red[k2][tid];
        const float v = (s + bias[2048] + 1.f) * 0.5f;
        out[(size_t)2 * HB + blockIdx.x * 32 + tid] = fminf(fmaxf(v, 0.f), 1.f);
    }
}

// ---------------------------------------------------------------------------
extern "C" void kernel_launch(void* const* d_in, const int* in_sizes, int n_in,
                              void* d_out, int out_size, void* d_ws, size_t ws_size,
                              hipStream_t stream) {
    const float* c    = (const float*)d_in[0];
    const float* hb   = (const float*)d_in[1];
    const float* h    = (const float*)d_in[2];
    const float* ht   = (const float*)d_in[3];
    const float* z    = (const float*)d_in[4];
    const float* zb   = (const float*)d_in[5];
    const float* U11  = (const float*)d_in[6];
    const float* U21  = (const float*)d_in[7];
    const float* W01  = (const float*)d_in[8];
    const float* bias = (const float*)d_in[9];
    float* out = (float*)d_out;

    char* ws = (char*)d_ws;
    bhalf* XtP = (bhalf*)ws;                       // 32*48*16KB = 25165824 B
    bhalf* WcP = (bhalf*)(ws + 25165824);          //  8*48*16KB =  6291456 B

    prep_x    <<<dim3(48, 32), 256, 0, stream>>>(h, ht, hb, z, zb, XtP);
    prep_w    <<<512, 256, 0, stream>>>(U11, U21, W01, WcP);
    gemm_fused<<<256, 512, 0, stream>>>(WcP, XtP, bias, c, h, z, zb, out);
    zhat_k    <<<256, 256, 0, stream>>>(XtP, U11, U21, W01, bias, out);
}

// Round 7
// 81.655 us; speedup vs baseline: 1.0455x; 1.0065x over previous
//
#include <hip/hip_runtime.h>
#include <hip/hip_bf16.h>

#define HH 512
#define BB 8192
#define KK 1536
#define NT 48              // K tiles of 32
#define HB 4194304         // 512*8192
#define BLOB 8192          // bhalf per 16KB blob

typedef __bf16 bhalf;
typedef __bf16 bf16x8 __attribute__((ext_vector_type(8)));
typedef float  f32x4  __attribute__((ext_vector_type(4)));

typedef __attribute__((address_space(1))) void* as1_t;
typedef __attribute__((address_space(3))) void* as3_t;

#define GLDS(src, dst) __builtin_amdgcn_global_load_lds((as1_t)(void*)(src), (as3_t)(void*)(dst), 16, 0, 0)
#define SBAR() asm volatile("s_barrier" ::: "memory")
#define VM8()  asm volatile("s_waitcnt vmcnt(8)" ::: "memory")
#define VM4()  asm volatile("s_waitcnt vmcnt(4)" ::: "memory")
#define VM0()  asm volatile("s_waitcnt vmcnt(0)" ::: "memory")

// Packed blob layout (k-major, conflict-free): blob = one (256-row, 32-k)
// tile = 16 KB.  slot s = rb*64 + hi*16 + lr.  Element (row rb*16+lr,
// k hi*8+e) at bhalf offset s*8+e.  Zero bank conflicts (verified R4).

// ---------------------------------------------------------------------------
// prep_x: pack scaled+transposed+bf16 X into blobs [nt][kt].
// ---------------------------------------------------------------------------
__global__ __launch_bounds__(256) void prep_x(
    const float* __restrict__ h, const float* __restrict__ ht,
    const float* __restrict__ hb, const float* __restrict__ z,
    const float* __restrict__ zb, bhalf* __restrict__ XtP)
{
    __shared__ float tile[32][257];
    const int tid = threadIdx.x;
    const int kt  = blockIdx.x;          // 0..47
    const int nt  = blockIdx.y;          // 0..31
    const int n   = nt * 256 + tid;
    const int kb  = kt * 32;

    const float* src; int kr; float scale;
    if (kb < 512)       { src = h;  kr = kb;        scale = 1.f - z[n]; }
    else if (kb < 1024) { src = ht; kr = kb - 512;  scale = z[n]; }
    else                { src = hb; kr = kb - 1024; scale = zb[n]; }

    #pragma unroll
    for (int kk = 0; kk < 32; ++kk)
        tile[kk][tid] = src[(size_t)(kr + kk) * BB + n] * scale;
    __syncthreads();

    bhalf* blob = XtP + (size_t)(nt * NT + kt) * BLOB;
    #pragma unroll
    for (int q = 0; q < 4; ++q) {
        const int s  = q * 256 + tid;
        const int rb = s >> 6, w = s & 63;
        const int hh = w >> 4, lrr = w & 15;      // slot = rb*64 + hh*16 + lrr
        const int nloc = rb * 16 + lrr, kloc = hh * 8;
        bf16x8 r;
        #pragma unroll
        for (int e = 0; e < 8; ++e) r[e] = (bhalf)tile[kloc + e][nloc];
        *(bf16x8*)(blob + s * 8) = r;
    }
}

// ---------------------------------------------------------------------------
// prep_w: pack gate-interleaved weights into blobs [mt][kt]; source-coalesced.
// ---------------------------------------------------------------------------
__global__ __launch_bounds__(256) void prep_w(
    const float* __restrict__ U11, const float* __restrict__ U21,
    const float* __restrict__ W01, bhalf* __restrict__ WcP)
{
    const int o    = blockIdx.x * 4 + (threadIdx.x >> 6);   // 0..2047
    const int lane = threadIdx.x & 63;
    const int g = o >> 9, j = o & 511;
    const int mp = 4 * j + g;
    const int mt = mp >> 8, rb = (mp >> 4) & 15, lrr = mp & 15;

    #pragma unroll
    for (int p = 0; p < 3; ++p) {
        const float* src = (p == 0) ? U11 : (p == 1) ? U21 : W01;
        const float* rp  = src + (size_t)o * 512 + lane * 8;
        float4 v0 = *(const float4*)rp;
        float4 v1 = *(const float4*)(rp + 4);
        bf16x8 r;
        r[0]=(bhalf)v0.x; r[1]=(bhalf)v0.y; r[2]=(bhalf)v0.z; r[3]=(bhalf)v0.w;
        r[4]=(bhalf)v1.x; r[5]=(bhalf)v1.y; r[6]=(bhalf)v1.z; r[7]=(bhalf)v1.w;
        const int kt = p * 16 + (lane >> 2);
        const int hh = lane & 3;
        *(bf16x8*)(WcP + (size_t)(mt * NT + kt) * BLOB
                   + rb * 512 + hh * 128 + lrr * 8) = r;
    }
}

// ---------------------------------------------------------------------------
__device__ __forceinline__ float sigmf(float x)    { return 1.f / (1.f + __expf(-x)); }
__device__ __forceinline__ float tanhfast(float x) { return 2.f / (1.f + __expf(-2.f * x)) - 1.f; }

// ---------------------------------------------------------------------------
// gemm_fused: BM=BN=256, 8 waves (2Mx4N), 4 LDS buffers of K-32 blobs,
// depth-3 counted-vmcnt prefetch, ONE barrier per K-tile.
// L2-locality XCD partition: each XCD owns 2 mt x 16 nt -> A panels (1.5 MB)
// L2-resident; B panels 2x L2 reuse.  (R6 had 8 mt x 4 nt = 9 MB thrash.)
// ---------------------------------------------------------------------------
__global__ __launch_bounds__(512, 2) void gemm_fused(
    const bhalf* __restrict__ WcP, const bhalf* __restrict__ XtP,
    const float* __restrict__ bias, const float* __restrict__ c_in,
    const float* __restrict__ h_in, const float* __restrict__ z,
    const float* __restrict__ zb, float* __restrict__ out)
{
    __shared__ bhalf As[4][BLOB];
    __shared__ bhalf Bs[4][BLOB];

    const int tid  = threadIdx.x;
    const int lane = tid & 63;
    const int wid  = tid >> 6;
    const int wm   = wid >> 2, wn = wid & 3;
    const int lr   = lane & 15, hi = lane >> 4;
    const int soff = hi * 128 + lr * 8;      // k-major fragment offset (bhalf)

    // XCD partition: xcd = bid&7 (HW round-robin).  XCD x gets
    // mt in {2(x&3), 2(x&3)+1}, nt in [16(x>>2), +16).  Bijective over 256.
    const int xcd = blockIdx.x & 7;
    const int i   = blockIdx.x >> 3;                 // 0..31
    const int mt  = ((xcd & 3) << 1) | (i & 1);      // 0..7
    const int nt  = ((xcd >> 2) << 4) | (i >> 1);    // 0..31
    const int m0 = mt * 256, n0 = nt * 256;

    const bhalf* gA = WcP + (size_t)mt * (NT * BLOB) + tid * 8;
    const bhalf* gB = XtP + (size_t)nt * (NT * BLOB) + tid * 8;

    const bhalf* pA0 = &As[0][wm * 4096 + soff];
    const bhalf* pA1 = &As[1][wm * 4096 + soff];
    const bhalf* pA2 = &As[2][wm * 4096 + soff];
    const bhalf* pA3 = &As[3][wm * 4096 + soff];
    const bhalf* pB0 = &Bs[0][wn * 2048 + soff];
    const bhalf* pB1 = &Bs[1][wn * 2048 + soff];
    const bhalf* pB2 = &Bs[2][wn * 2048 + soff];
    const bhalf* pB3 = &Bs[3][wn * 2048 + soff];

#define STAGE(t, bf) do {                                                     \
        const bhalf* sa_ = gA + (size_t)(t) * BLOB;                           \
        const bhalf* sb_ = gB + (size_t)(t) * BLOB;                           \
        GLDS(sa_, &As[bf][tid * 8]); GLDS(sa_ + 4096, &As[bf][tid * 8 + 4096]); \
        GLDS(sb_, &Bs[bf][tid * 8]); GLDS(sb_ + 4096, &Bs[bf][tid * 8 + 4096]); \
    } while (0)

#define MF(mi, ni, A_, B_) acc[mi][ni] = \
    __builtin_amdgcn_mfma_f32_16x16x32_bf16(A_, B_, acc[mi][ni], 0, 0, 0)

// one K-32 tile from buffer q: 12 ds_read_b128 + 32 MFMA, compiler-scheduled
#define CT(q) do {                                                            \
    bf16x8 b0 = *(const bf16x8*)(pB##q);                                      \
    bf16x8 b1 = *(const bf16x8*)(pB##q + 512);                                \
    bf16x8 b2 = *(const bf16x8*)(pB##q + 1024);                               \
    bf16x8 b3 = *(const bf16x8*)(pB##q + 1536);                               \
    bf16x8 a0 = *(const bf16x8*)(pA##q);                                      \
    bf16x8 a1 = *(const bf16x8*)(pA##q + 512);                                \
    bf16x8 a2 = *(const bf16x8*)(pA##q + 1024);                               \
    bf16x8 a3 = *(const bf16x8*)(pA##q + 1536);                               \
    bf16x8 a4 = *(const bf16x8*)(pA##q + 2048);                               \
    bf16x8 a5 = *(const bf16x8*)(pA##q + 2560);                               \
    bf16x8 a6 = *(const bf16x8*)(pA##q + 3072);                               \
    bf16x8 a7 = *(const bf16x8*)(pA##q + 3584);                               \
    __builtin_amdgcn_s_setprio(1);                                            \
    MF(0,0,a0,b0); MF(0,1,a0,b1); MF(0,2,a0,b2); MF(0,3,a0,b3);               \
    MF(1,0,a1,b0); MF(1,1,a1,b1); MF(1,2,a1,b2); MF(1,3,a1,b3);               \
    MF(2,0,a2,b0); MF(2,1,a2,b1); MF(2,2,a2,b2); MF(2,3,a2,b3);               \
    MF(3,0,a3,b0); MF(3,1,a3,b1); MF(3,2,a3,b2); MF(3,3,a3,b3);               \
    MF(4,0,a4,b0); MF(4,1,a4,b1); MF(4,2,a4,b2); MF(4,3,a4,b3);               \
    MF(5,0,a5,b0); MF(5,1,a5,b1); MF(5,2,a5,b2); MF(5,3,a5,b3);               \
    MF(6,0,a6,b0); MF(6,1,a6,b1); MF(6,2,a6,b2); MF(6,3,a6,b3);               \
    MF(7,0,a7,b0); MF(7,1,a7,b1); MF(7,2,a7,b2); MF(7,3,a7,b3);               \
    __builtin_amdgcn_s_setprio(0);                                            \
} while (0)

    f32x4 acc[8][4] = {};

    // prologue: stage tiles 0..2 (12 gloads in flight)
    STAGE(0, 0); STAGE(1, 1); STAGE(2, 2);

    // tiles 0..43: steady state; vmcnt(8) waits tile t's 4 loads, one barrier.
    for (int base = 0; base < 44; base += 4) {
        VM8(); SBAR(); STAGE(base + 3, 3); CT(0);
        VM8(); SBAR(); STAGE(base + 4, 0); CT(1);
        VM8(); SBAR(); STAGE(base + 5, 1); CT(2);
        VM8(); SBAR(); STAGE(base + 6, 2); CT(3);
    }
    // t=44: stage 47 -> buf3; t=45..47 drain 8/4/0
    VM8(); SBAR(); STAGE(47, 3); CT(0);
    VM8(); SBAR(); CT(1);
    VM4(); SBAR(); CT(2);
    VM0(); SBAR(); CT(3);

    // ---- fused gate epilogue: acc[mi][ni][r] = gate r of hidden j ----
    const int colbase = n0 + wn * 64 + lr;
    float zc[4], zbc[4];
    #pragma unroll
    for (int ni = 0; ni < 4; ++ni) {
        zc[ni]  = z[colbase + ni * 16];
        zbc[ni] = zb[colbase + ni * 16];
    }
    #pragma unroll
    for (int mi = 0; mi < 8; ++mi) {
        const int j = (m0 >> 2) + wm * 32 + mi * 4 + hi;
        const float bf_ = bias[j];
        const float bi_ = bias[512 + j];
        const float bo_ = bias[1024 + j];
        const float bg_ = bias[1536 + j];
        #pragma unroll
        for (int ni = 0; ni < 4; ++ni) {
            const int col = colbase + ni * 16;
            const size_t idx = (size_t)j * BB + col;
            const float cv = c_in[idx];
            const float hv = h_in[idx];
            const float fv = sigmf(acc[mi][ni][0] + bf_);
            const float iv = sigmf(acc[mi][ni][1] + bi_);
            const float ov = sigmf(acc[mi][ni][2] + bo_);
            const float gv = tanhfast(acc[mi][ni][3] + bg_);
            const float ig = iv * gv;
            const float zq = zc[ni], zbq = zbc[ni];
            const float cn = zq * ig + (1.f - zq) * (1.f - zbq) * cv
                           + (1.f - zq) * zbq * (fv * cv + ig);
            const float tc = tanhfast(cn);
            const float hn = (zq + (1.f - zq) * zbq) * ov * tc
                           + (1.f - zq) * (1.f - zbq) * hv;
            out[idx]      = hn;
            out[HB + idx] = cn;
        }
    }
}

// ---------------------------------------------------------------------------
// zhat: row 2048 GEMV over packed Xt (bf16).
// ---------------------------------------------------------------------------
__global__ __launch_bounds__(256) void zhat_k(
    const bhalf* __restrict__ XtP, const float* __restrict__ U11,
    const float* __restrict__ U21, const float* __restrict__ W01,
    const float* __restrict__ bias, float* __restrict__ out)
{
    __shared__ float wlds[1536];
    __shared__ float red[8][32];
    const int tid = threadIdx.x;
    for (int idx = tid; idx < 1536; idx += 256) {
        float v;
        if (idx < 512)       v = U11[1048576 + idx];
        else if (idx < 1024) v = U21[1048576 + idx - 512];
        else                 v = W01[1048576 + idx - 1024];
        wlds[idx] = v;
    }
    __syncthreads();

    const int col = tid & 31, kg = tid >> 5;
    const int n = blockIdx.x * 32 + col;
    const int nt = n >> 8, rb = (n >> 4) & 15, lrr = n & 15;
    const bhalf* base = XtP + (size_t)nt * (NT * BLOB) + rb * 512;

    float acc = 0.f;
    for (int kt = kg * 6; kt < kg * 6 + 6; ++kt) {
        #pragma unroll
        for (int hh = 0; hh < 4; ++hh) {
            bf16x8 v = *(const bf16x8*)(base + (size_t)kt * BLOB + hh * 128 + lrr * 8);
            #pragma unroll
            for (int e = 0; e < 8; ++e)
                acc += (float)v[e] * wlds[kt * 32 + hh * 8 + e];
        }
    }
    red[kg][col] = acc;
    __syncthreads();
    if (tid < 32) {
        float s = 0.f;
        #pragma unroll
        for (int k2 = 0; k2 < 8; ++k2) s += red[k2][tid];
        const float v = (s + bias[2048] + 1.f) * 0.5f;
        out[(size_t)2 * HB + blockIdx.x * 32 + tid] = fminf(fmaxf(v, 0.f), 1.f);
    }
}

// ---------------------------------------------------------------------------
extern "C" void kernel_launch(void* const* d_in, const int* in_sizes, int n_in,
                              void* d_out, int out_size, void* d_ws, size_t ws_size,
                              hipStream_t stream) {
    const float* c    = (const float*)d_in[0];
    const float* hb   = (const float*)d_in[1];
    const float* h    = (const float*)d_in[2];
    const float* ht   = (const float*)d_in[3];
    const float* z    = (const float*)d_in[4];
    const float* zb   = (const float*)d_in[5];
    const float* U11  = (const float*)d_in[6];
    const float* U21  = (const float*)d_in[7];
    const float* W01  = (const float*)d_in[8];
    const float* bias = (const float*)d_in[9];
    float* out = (float*)d_out;

    char* ws = (char*)d_ws;
    bhalf* XtP = (bhalf*)ws;                       // 32*48*16KB = 25165824 B
    bhalf* WcP = (bhalf*)(ws + 25165824);          //  8*48*16KB =  6291456 B

    prep_x    <<<dim3(48, 32), 256, 0, stream>>>(h, ht, hb, z, zb, XtP);
    prep_w    <<<512, 256, 0, stream>>>(U11, U21, W01, WcP);
    gemm_fused<<<256, 512, 0, stream>>>(WcP, XtP, bias, c, h, z, zb, out);
    zhat_k    <<<256, 256, 0, stream>>>(XtP, U11, U21, W01, bias, out);
}